// Round 6
// baseline (150.533 us; speedup 1.0000x reference)
//
#include <hip/hip_runtime.h>

// SPD loss: 18-bin (9 class x 2 group) histogram over 16.7M int32 pairs + tiny epilogue.
// R0-R2: LDS atomics -> reg histogram -> no global atomics: 45-55 us, warm==cold.
// R3-R5,R7: four attempts to force per-wave MLP at HIP level (source burst,
//     launch_bounds, asm reg pins, pinned double-buffer) — backend undid all.
// R8: loads + counted vmcnt(14..0) emitted IN inline asm — pipeline guaranteed
//     at ISA level, ~512 KB/CU demanded from t=0. STILL 44-46 us @ 3.05 TB/s.
//     => not latency-bound: this measures the DELIVERY ceiling. m13 copy 6.29
//     TB/s = ~3.15 read + ~3.15 write; no documented kernel reads >3.15 TB/s;
//     warm(L3)==cold(HBM) => cap is between L2/L3 and CU, not HBM.
//     (VGPR_Count column is bogus — 44 reported with 64 asm outputs live.)
// R9 (this): LAST discriminator — the other return path. global_load_lds
//     LDS-DMA (no VGPR writeback): per-wave quad-buffered pipeline, each wave
//     stages its own 2x1KB per round, counted vmcnt(6) consume + restage,
//     never drains to 0, no barriers in the loop, ds_read via asm.
//     Fork A (universal read cap ~3.1 TB/s): dur stays 44-47 -> ROOFLINE.
//     Fork B (VGPR-return path was the limit): dur -> 25-35 us.

#define N_CLASSES 9
#define N_GROUPS 2
#define NBINS (N_CLASSES * N_GROUPS)  // 18
#define BDIM 512
#define NBUF 4                         // LDS quad-buffer depth

typedef int vint4 __attribute__((ext_vector_type(4)));
typedef __attribute__((address_space(1))) const void as1_cvoid;
typedef __attribute__((address_space(3))) void as3_void;

__global__ __launch_bounds__(BDIM, 2) void spd_hist_kernel(
    const int* __restrict__ preds,
    const int* __restrict__ attrs,
    unsigned int* __restrict__ partials,  // [gridDim.x][NBINS]
    int n4, int n)
{
    __shared__ vint4 sp[NBUF][BDIM];      // preds landing pads (4 x 8 KB)
    __shared__ vint4 sa[NBUF][BDIM];      // attrs landing pads (4 x 8 KB)
    __shared__ unsigned int lh0[N_CLASSES];
    __shared__ unsigned int lh1[N_CLASSES];
    if (threadIdx.x < N_CLASSES) { lh0[threadIdx.x] = 0u; lh1[threadIdx.x] = 0u; }
    __syncthreads();

    // per-thread 16-bit packed totals: lo16 = group0, hi16 = group1
    unsigned int cnt[N_CLASSES];
    #pragma unroll
    for (int p = 0; p < N_CLASSES; ++p) cnt[p] = 0u;

    const vint4* __restrict__ p4 = (const vint4*)preds;
    const vint4* __restrict__ a4 = (const vint4*)attrs;

    const int wave = (int)threadIdx.x >> 6;
    const int lane = (int)threadIdx.x & 63;

    const int F = n4 / BDIM;                 // full 512-int4 rounds in the input
    // rounds owned by this block: j such that blockIdx.x + j*grid < F
    const int K = ((int)blockIdx.x < F)
                ? ((F - 1 - (int)blockIdx.x) / (int)gridDim.x + 1) : 0;

    unsigned long long accT = 0ull, acc1 = 0ull;   // 9 x 7-bit packed counters

    // stage round j into LDS slot b: per-wave DMA, 2 x (64 lanes x 16 B).
    // LDS dest is wave-uniform base + lane*16 (HW rule) — layout matches.
    #define STAGE(b, j) { \
        size_t g_ = ((size_t)blockIdx.x + (size_t)(j) * gridDim.x) * BDIM + (size_t)(wave * 64 + lane); \
        __builtin_amdgcn_global_load_lds((as1_cvoid*)(p4 + g_), (as3_void*)&sp[b][wave * 64], 16, 0, 0); \
        __builtin_amdgcn_global_load_lds((as1_cvoid*)(a4 + g_), (as3_void*)&sa[b][wave * 64], 16, 0, 0); \
    }

    #define CONS1(P, A) { \
        { unsigned long long inc = 1ull << (7 * P.x); accT += inc; acc1 += (A.x == 0) ? 0ull : inc; } \
        { unsigned long long inc = 1ull << (7 * P.y); accT += inc; acc1 += (A.y == 0) ? 0ull : inc; } \
        { unsigned long long inc = 1ull << (7 * P.z); accT += inc; acc1 += (A.z == 0) ? 0ull : inc; } \
        { unsigned long long inc = 1ull << (7 * P.w); accT += inc; acc1 += (A.w == 0) ? 0ull : inc; } \
    }

    #define FLUSH { \
        _Pragma("unroll") \
        for (int p = 0; p < N_CLASSES; ++p) { \
            unsigned int ct = (unsigned int)(accT >> (7 * p)) & 127u; \
            unsigned int c1 = (unsigned int)(acc1 >> (7 * p)) & 127u; \
            cnt[p] += (ct - c1) | (c1 << 16); \
        } \
        accT = 0ull; acc1 = 0ull; \
    }

    // consume slot b with counted wait VM (per-wave vmcnt: 2 loads/stage,
    // NBUF stages in flight -> steady-state wait = 2*(NBUF-1) = 6, never 0).
    // ds_read via asm so the compiler cannot insert a conservative vmcnt(0)
    // drain before reading DMA-written LDS; lgkmcnt(0) + sched_barrier per
    // guide rule #18 before the restage overwrites the slot.
    #define PIPE(b, VM, DO_STAGE, jn) { \
        asm volatile("s_waitcnt vmcnt(" #VM ")" ::: "memory"); \
        __builtin_amdgcn_sched_barrier(0); \
        unsigned po_ = (unsigned)(uintptr_t)(as3_void*)&sp[b][threadIdx.x]; \
        unsigned ao_ = (unsigned)(uintptr_t)(as3_void*)&sa[b][threadIdx.x]; \
        vint4 pp_, aa_; \
        asm volatile("ds_read_b128 %0, %2\n\t" \
                     "ds_read_b128 %1, %3\n\t" \
                     "s_waitcnt lgkmcnt(0)" \
            : "=&v"(pp_), "=&v"(aa_) : "v"(po_), "v"(ao_) : "memory"); \
        __builtin_amdgcn_sched_barrier(0); \
        if (DO_STAGE) STAGE(b, jn) \
        CONS1(pp_, aa_) \
    }

    if (K >= NBUF) {
        // prologue: fill all 4 slots (8 DMAs in flight per wave)
        STAGE(0, 0) STAGE(1, 1) STAGE(2, 2) STAGE(3, 3)
        int base = 0;
        for (; base + 2 * NBUF <= K; base += NBUF) {
            PIPE(0, 6, 1, base + 4)
            PIPE(1, 6, 1, base + 5)
            PIPE(2, 6, 1, base + 6)
            PIPE(3, 6, 1, base + 7)
            FLUSH              // <=16 per 7-bit field per cycle: safe
        }
        // epilogue: slots hold rounds base..base+3; drain 6/4/2/0
        PIPE(0, 6, 0, 0)
        PIPE(1, 4, 0, 0)
        PIPE(2, 2, 0, 0)
        PIPE(3, 0, 0, 0)
        // leftover full rounds (at most 3) via direct loads
        for (int j = base + 4; j < K; ++j) {
            size_t g = ((size_t)blockIdx.x + (size_t)j * gridDim.x) * BDIM + threadIdx.x;
            vint4 pp = p4[g], aa = a4[g];
            CONS1(pp, aa)
        }
        FLUSH                  // <=28 per field: safe
    } else {
        for (int j = 0; j < K; ++j) {
            size_t g = ((size_t)blockIdx.x + (size_t)j * gridDim.x) * BDIM + threadIdx.x;
            vint4 pp = p4[g], aa = a4[g];
            CONS1(pp, aa)
        }
        FLUSH
    }

    // partial round F (n4 % BDIM int4s), one designated block, guarded loads
    if ((n4 % BDIM) && (int)blockIdx.x == (F % (int)gridDim.x)) {
        size_t g = (size_t)F * BDIM + threadIdx.x;
        if (g < (size_t)n4) {
            vint4 pp = p4[g], aa = a4[g];
            CONS1(pp, aa)
        }
        FLUSH
    }

    #undef PIPE
    #undef FLUSH
    #undef CONS1
    #undef STAGE

    // scalar remainder (n % 4), block 0 only: <=3 items
    if (blockIdx.x == 0) {
        for (int t = n4 * 4 + (int)threadIdx.x; t < n; t += BDIM)
            cnt[preds[t]] += (attrs[t] == 0) ? 1u : 0x10000u;
    }

    // wave-64 butterfly; 16-bit halves stay far below 65536 for this N
    #pragma unroll
    for (int m = 1; m < 64; m <<= 1) {
        #pragma unroll
        for (int p = 0; p < N_CLASSES; ++p)
            cnt[p] += __shfl_xor(cnt[p], m, 64);
    }

    // wave leaders -> block LDS (u32 per group)
    if ((threadIdx.x & 63) == 0) {
        #pragma unroll
        for (int p = 0; p < N_CLASSES; ++p) {
            atomicAdd(&lh0[p], cnt[p] & 0xFFFFu);
            atomicAdd(&lh1[p], cnt[p] >> 16);
        }
    }
    __syncthreads();

    // plain stores — no global atomics
    if (threadIdx.x < NBINS) {
        int c = threadIdx.x >> 1;
        unsigned int v = (threadIdx.x & 1) ? lh1[c] : lh0[c];
        partials[blockIdx.x * NBINS + threadIdx.x] = v;
    }
}

__global__ __launch_bounds__(1024) void spd_finalize_kernel(
    const unsigned int* __restrict__ partials,
    float* __restrict__ out, int nblocks, double n_total)
{
    __shared__ double counts[NBINS];
    const int tid = threadIdx.x;

    if (tid < NBINS * 32) {
        const int bin = tid >> 5;
        const int j = tid & 31;
        unsigned int s = 0u;
        #pragma unroll 8
        for (int b = j; b < nblocks; b += 32)
            s += partials[b * NBINS + bin];
        #pragma unroll
        for (int m = 1; m < 32; m <<= 1)
            s += __shfl_xor(s, m, 32);
        if (j == 0) counts[bin] = (double)s;
    }
    __syncthreads();

    if (tid == 0) {
        double n1 = 0.0;
        #pragma unroll
        for (int c = 0; c < N_CLASSES; ++c)
            n1 += counts[c * N_GROUPS + 1];
        double n0 = n_total - n1;
        double acc = 0.0;
        #pragma unroll
        for (int c = 0; c < N_CLASSES; ++c) {
            double d = counts[c * N_GROUPS] / n0 - counts[c * N_GROUPS + 1] / n1;
            acc += d * d;
        }
        out[0] = (float)acc;
    }
}

extern "C" void kernel_launch(void* const* d_in, const int* in_sizes, int n_in,
                              void* d_out, int out_size, void* d_ws, size_t ws_size,
                              hipStream_t stream)
{
    const int* preds = (const int*)d_in[0];
    const int* attrs = (const int*)d_in[1];
    const int n = in_sizes[0];

    unsigned int* partials = (unsigned int*)d_ws;

    const int n4 = n / 4;
    const int F = n4 / BDIM;                          // full rounds (8192 here)
    int grid = 512;                                   // 2 blocks/CU (64 KB LDS each), K=16
    if (grid > F) grid = (F > 0) ? F : 1;
    int max_grid = (int)(ws_size / (NBINS * sizeof(unsigned int)));
    if (grid > max_grid) grid = max_grid;
    if (grid < 1) grid = 1;

    spd_hist_kernel<<<grid, BDIM, 0, stream>>>(preds, attrs, partials, n4, n);
    spd_finalize_kernel<<<1, 1024, 0, stream>>>(partials, (float*)d_out, grid, (double)n);
}